// Round 7
// baseline (485.231 us; speedup 1.0000x reference)
//
#include <hip/hip_runtime.h>
#include <math.h>

// Problem constants
#define B_DIM 32
#define C_DIM 1024
#define MAP 784
#define NMASK 153
#define NTERM 154          // 153 masks + global-max term
#define NROW 192           // padded row length (3 x 64 lanes; pads = 0)
#define NBIN 77            // 0=center, 1 + q*19 + (r-1)
#define DUMMY_BIN 77
#define MAX1 28            // slots for each lane's primary bin
#define MAX2 6             // slots for secondary (small) bins on lanes 51..63
#define MPW 8              // maps per wave; 1024 blocks x 4 waves x 8 = 32768
#define NBLK 1024

// ---------------------------------------------------------------------------
// Compile-time gather schedule, bank-aware (verified rounds 3-6, unchanged).
// ---------------------------------------------------------------------------
struct Sched {
    unsigned short off1[MAX1][64];  // [slot][lane] byte offset, primary bin
    unsigned short off2[MAX2][64];  // [slot][lane] byte offset, secondary bin
    unsigned char  binA[64];
    unsigned char  binB[64];        // DUMMY_BIN for lanes without a 2nd bin
    bool ok;
};

constexpr Sched build_sched() {
    Sched S{};
    S.ok = true;
    short px[NBIN][40] = {};
    int   n[NBIN] = {};
    for (int i = 0; i < 28; ++i)
        for (int j = 0; j < 28; ++j) {
            int dy = i - 14, dx = j - 14, r2 = dx * dx + dy * dy;
            int p = i * 28 + j;
            if (r2 == 0) { px[0][n[0]++] = (short)p; continue; }
            if (r2 > 361) continue;            // r2>361: in NO mask
            int r = 0; while (r * r < r2) ++r; // ceil(sqrt), 1..19
            const int sx[4] = {1, -1, 1, -1}, sy[4] = {1, 1, -1, -1};
            for (int q = 0; q < 4; ++q)
                if (sx[q] * dx >= 0 && sy[q] * dy >= 0) {
                    int b = 1 + q * 19 + (r - 1);
                    if (n[b] >= 40) { S.ok = false; continue; }
                    px[b][n[b]++] = (short)p;
                }
        }
    int ord[NBIN] = {};
    for (int k = 0; k < NBIN; ++k) ord[k] = k;
    for (int a = 0; a < NBIN; ++a) {
        int best = a;
        for (int c = a + 1; c < NBIN; ++c)
            if (n[ord[c]] > n[ord[best]]) best = c;
        int t = ord[a]; ord[a] = ord[best]; ord[best] = t;
    }
    for (int l = 0; l < 64; ++l) {
        S.binA[l] = (unsigned char)ord[l];
        S.binB[l] = (l >= 51) ? (unsigned char)ord[64 + (l - 51)]
                              : (unsigned char)DUMMY_BIN;
        if (n[ord[l]] > MAX1) S.ok = false;
        if (l >= 51 && n[ord[64 + (l - 51)]] > MAX2) S.ok = false;
    }
    {   // greedy bank-aware placement, primary loop
        bool used[64][40] = {};
        for (int s = 0; s < MAX1; ++s) {
            int bankcnt[32] = {};
            for (int l = 0; l < 64; ++l) {
                int bin = S.binA[l], cnt = n[bin];
                int bestp = 0, bestload = 1 << 30; bool haveUnused = false;
                for (int t = 0; t < cnt; ++t)
                    if (!used[l][t]) {
                        int load = bankcnt[px[bin][t] % 32];
                        if (!haveUnused || load < bestload) { haveUnused = true; bestload = load; bestp = t; }
                    }
                if (!haveUnused)
                    for (int t = 0; t < cnt; ++t) {
                        int load = bankcnt[px[bin][t] % 32];
                        if (load < bestload) { bestload = load; bestp = t; }
                    }
                int p = px[bin][bestp];
                if (haveUnused) used[l][bestp] = true;
                S.off1[s][l] = (unsigned short)(p * 4);
                bankcnt[p % 32]++;
            }
        }
        for (int l = 0; l < 64; ++l)
            for (int t = 0; t < n[S.binA[l]]; ++t)
                if (!used[l][t]) S.ok = false;
    }
    {   // secondary loop
        bool used[64][40] = {};
        for (int s = 0; s < MAX2; ++s) {
            int bankcnt[32] = {};
            for (int l = 0; l < 64; ++l) {
                if (S.binB[l] == DUMMY_BIN) {
                    S.off2[s][l] = (unsigned short)((l % 32) * 4);
                    continue;
                }
                int bin = S.binB[l], cnt = n[bin];
                int bestp = 0, bestload = 1 << 30; bool haveUnused = false;
                for (int t = 0; t < cnt; ++t)
                    if (!used[l][t]) {
                        int load = bankcnt[px[bin][t] % 32];
                        if (!haveUnused || load < bestload) { haveUnused = true; bestload = load; bestp = t; }
                    }
                if (!haveUnused)
                    for (int t = 0; t < cnt; ++t) {
                        int load = bankcnt[px[bin][t] % 32];
                        if (load < bestload) { bestload = load; bestp = t; }
                    }
                int p = px[bin][bestp];
                if (haveUnused) used[l][bestp] = true;
                S.off2[s][l] = (unsigned short)(p * 4);
                bankcnt[p % 32]++;
            }
        }
        for (int l = 0; l < 64; ++l)
            if (S.binB[l] != DUMMY_BIN)
                for (int t = 0; t < n[S.binB[l]]; ++t)
                    if (!used[l][t]) S.ok = false;
    }
    return S;
}

static_assert(build_sched().ok, "schedule overflow / unplaced pixel");
__constant__ Sched d_sched = build_sched();

// sbuf per-wave layout: [0..76] bins, [77] dummy, [78..153] circles(q*19+r-1)
__device__ __forceinline__ int term_addr(int k) {
    if (k == 0) return 0;                    // center mask
    if (k >= NMASK) return DUMMY_BIN;        // 153 overridden w/ gmax; >153 -> 0
    int t = k - 1, q = (t >> 1) & 3, rm1 = t >> 3;
    return (t & 1) ? 78 + q * 19 + rm1       // circle
                   : 1 + q * 19 + rm1;       // ring
}

// ---------------------------------------------------------------------------
// Fused kernel: rows in registers across a manual device-scope grid barrier.
// 1024 blocks x 256 thr, __launch_bounds__(256,4) -> 4 blocks/CU co-resident.
// ---------------------------------------------------------------------------
__global__ __launch_bounds__(256, 4) void cac_fused(const float* __restrict__ x,
                                                    float* __restrict__ partial,
                                                    unsigned* __restrict__ barrier_cnt,
                                                    float* __restrict__ out) {
    __shared__ __align__(16) float smap[4][MAP];
    __shared__ float sbuf[4][160];           // bins + circles per wave
    __shared__ float ssqred[4][NROW];
    __shared__ __align__(16) float sinv[NROW];

    const int wave = threadIdx.x >> 6;
    const int lane = threadIdx.x & 63;
    const int bk = blockIdx.x;
    const int pair0 = bk * 32 + wave * MPW;
    const int b = bk >> 5;                   // 32 blocks per batch index

    // hoisted per-lane constants
    const int linA = lane % 19;                          // segment pos (q0-q2)
    const bool inA = lane < 57, inB = lane < 19;
    const int rbA = 1 + lane;                            // lanes>=57 read q3: harmless
    const int rbB = inB ? 58 + lane : DUMMY_BIN;
    const int a0 = term_addr(lane);
    const int a1 = term_addr(lane + 64);
    const int a2 = term_addr(lane + 128);

    // prefetch map 0
    const float4 NEG4 = make_float4(-INFINITY, -INFINITY, -INFINITY, -INFINITY);
    const float4* xp4 = (const float4*)(x + (size_t)pair0 * MAP);
    float4 t0 = xp4[lane], t1 = xp4[64 + lane], t2 = xp4[128 + lane];
    float4 t3 = NEG4;
    if (lane < 4) t3 = xp4[192 + lane];

    float* smw = smap[wave];
    float* sbw = sbuf[wave];
    float sq0 = 0.0f, sq1 = 0.0f, sq2 = 0.0f;
    float r0a[MPW], r1a[MPW], r2a[MPW];      // rows live in registers

    #pragma unroll
    for (int m = 0; m < MPW; ++m) {
        ((float4*)smw)[lane]       = t0;
        ((float4*)smw)[64 + lane]  = t1;
        ((float4*)smw)[128 + lane] = t2;
        if (lane < 4) ((float4*)smw)[192 + lane] = t3;
        float gmax = fmaxf(fmaxf(fmaxf(t0.x, t0.y), fmaxf(t0.z, t0.w)),
                           fmaxf(fmaxf(t1.x, t1.y), fmaxf(t1.z, t1.w)));
        gmax = fmaxf(gmax, fmaxf(fmaxf(t2.x, t2.y), fmaxf(t2.z, t2.w)));
        gmax = fmaxf(gmax, fmaxf(fmaxf(t3.x, t3.y), fmaxf(t3.z, t3.w)));

        if (m < MPW - 1) {   // software-pipeline next map's global loads
            const float4* np4 = (const float4*)(x + (size_t)(pair0 + m + 1) * MAP);
            t0 = np4[lane]; t1 = np4[64 + lane]; t2 = np4[128 + lane];
            t3 = NEG4;
            if (lane < 4) t3 = np4[192 + lane];
        }
        __builtin_amdgcn_wave_barrier();     // keep LDS writes before reads

        // bank-scheduled gather (init 0 == masked-max clamp)
        const char* base = (const char*)smw;
        float m1 = 0.0f, m2v = 0.0f;
        #pragma unroll
        for (int s = 0; s < MAX1; ++s)
            m1 = fmaxf(m1, *(const float*)(base + d_sched.off1[s][lane]));
        #pragma unroll
        for (int s = 0; s < MAX2; ++s)
            m2v = fmaxf(m2v, *(const float*)(base + d_sched.off2[s][lane]));
        sbw[d_sched.binA[lane]] = m1;
        sbw[d_sched.binB[lane]] = m2v;       // dummy slot absorbs pad lanes

        #pragma unroll
        for (int off = 32; off; off >>= 1)
            gmax = fmaxf(gmax, __shfl_xor(gmax, off, 64));
        __builtin_amdgcn_wave_barrier();

        // segmented shuffle prefix-max over rings -> circles
        float cval = sbw[0];
        float rA = fmaxf(sbw[rbA], cval);    // rings: q=lane/19, r=lane%19+1
        float rB = fmaxf(sbw[rbB], cval);    // q3 rings on lanes 0..18
        #pragma unroll
        for (int s = 1; s <= 16; s <<= 1) {
            float uA = __shfl_up(rA, s, 64);
            float uB = __shfl_up(rB, s, 64);
            if (linA >= s) rA = fmaxf(rA, uA);
            if (lane >= s) rB = fmaxf(rB, uB);
        }
        if (inA) sbw[78 + lane] = rA;
        if (inB) sbw[135 + lane] = rB;
        __builtin_amdgcn_wave_barrier();

        // terms from one LDS read each -> registers
        float r0 = sbw[a0];
        float r1 = sbw[a1];
        float r2 = sbw[a2];
        r2 = (lane == 25) ? gmax : (lane < 26 ? r2 : 0.0f);  // k=153 / pads
        r0a[m] = r0; r1a[m] = r1; r2a[m] = r2;
        sq0 += r0 * r0; sq1 += r1 * r1; sq2 += r2 * r2;
        __builtin_amdgcn_wave_barrier();     // next map's bin writes must not race
    }

    // block-level partial sum of squares -> global (786 KB total)
    ssqred[wave][lane]       = sq0;
    ssqred[wave][lane + 64]  = sq1;
    ssqred[wave][lane + 128] = sq2;
    __syncthreads();
    if (threadIdx.x < NROW) {
        int t = threadIdx.x;
        partial[(size_t)bk * NROW + t] =
            ssqred[0][t] + ssqred[1][t] + ssqred[2][t] + ssqred[3][t];
    }

    // ---- manual grid barrier (device-scope; all 1024 blocks co-resident) ----
    __threadfence();                         // make partial[] visible device-wide
    __syncthreads();
    if (threadIdx.x == 0) {
        __hip_atomic_fetch_add(barrier_cnt, 1u, __ATOMIC_RELEASE,
                               __HIP_MEMORY_SCOPE_AGENT);
        while (__hip_atomic_load(barrier_cnt, __ATOMIC_ACQUIRE,
                                 __HIP_MEMORY_SCOPE_AGENT) < (unsigned)NBLK)
            __builtin_amdgcn_s_sleep(2);
    }
    __syncthreads();
    __threadfence();                         // acquire for all threads

    // ---- redundant per-block norm reduce: 32 partial rows of own b (L2) ----
    if (threadIdx.x < NROW) {
        int t = threadIdx.x;
        const float* p = partial + (size_t)(b * 32) * NROW + t;
        float s = 0.0f;
        #pragma unroll
        for (int j = 0; j < 32; ++j) s += p[j * NROW];   // coalesced over t
        sinv[t] = (t < NTERM) ? 1.0f / (sqrtf(s) + 1e-6f) : 0.0f;
    }
    __syncthreads();

    // ---- dot(row, invn) from registers; shuffle-reduce per map ----
    float w0 = sinv[lane];
    float w1 = sinv[64 + lane];
    float w2 = sinv[128 + lane];             // pads are 0
    #pragma unroll
    for (int m = 0; m < MPW; ++m) {
        float d = r0a[m] * w0 + r1a[m] * w1 + r2a[m] * w2;
        #pragma unroll
        for (int off = 32; off; off >>= 1) d += __shfl_xor(d, off, 64);
        if (lane == 0) out[pair0 + m] = d;
    }
}

extern "C" void kernel_launch(void* const* d_in, const int* in_sizes, int n_in,
                              void* d_out, int out_size, void* d_ws, size_t ws_size,
                              hipStream_t stream) {
    const float* x = (const float*)d_in[0];
    float* out = (float*)d_out;

    unsigned* barrier_cnt = (unsigned*)d_ws;                  // [0..255] barrier
    float* partial = (float*)((char*)d_ws + 256);             // 1024*192 f32 = 786 KB

    hipMemsetAsync(d_ws, 0, 256, stream);                     // graph-capture legal
    cac_fused<<<NBLK, 256, 0, stream>>>(x, partial, barrier_cnt, out);
}

// Round 8
// 419.085 us; speedup vs baseline: 1.1578x; 1.1578x over previous
//
#include <hip/hip_runtime.h>
#include <math.h>

// Problem constants
#define B_DIM 32
#define C_DIM 1024
#define MAP 784
#define NMASK 153
#define NTERM 154          // 153 masks + global-max term
#define NROW 192           // padded row length (3 x 64 lanes; pads = 0)
#define NBIN 77            // 0=center, 1 + q*19 + (r-1)
#define DUMMY_BIN 77
#define MAX1 28            // slots for each lane's primary bin
#define MAX2 6             // slots for secondary (small) bins on lanes 51..63
#define MPW 8              // maps per wave; 1024 blocks x 4 waves x 8 = 32768
#define NBLK 1024

// ---------------------------------------------------------------------------
// Compile-time gather schedule, bank-aware (verified rounds 3-7, unchanged).
// ---------------------------------------------------------------------------
struct Sched {
    unsigned short off1[MAX1][64];  // [slot][lane] byte offset, primary bin
    unsigned short off2[MAX2][64];  // [slot][lane] byte offset, secondary bin
    unsigned char  binA[64];
    unsigned char  binB[64];        // DUMMY_BIN for lanes without a 2nd bin
    bool ok;
};

constexpr Sched build_sched() {
    Sched S{};
    S.ok = true;
    short px[NBIN][40] = {};
    int   n[NBIN] = {};
    for (int i = 0; i < 28; ++i)
        for (int j = 0; j < 28; ++j) {
            int dy = i - 14, dx = j - 14, r2 = dx * dx + dy * dy;
            int p = i * 28 + j;
            if (r2 == 0) { px[0][n[0]++] = (short)p; continue; }
            if (r2 > 361) continue;            // r2>361: in NO mask
            int r = 0; while (r * r < r2) ++r; // ceil(sqrt), 1..19
            const int sx[4] = {1, -1, 1, -1}, sy[4] = {1, 1, -1, -1};
            for (int q = 0; q < 4; ++q)
                if (sx[q] * dx >= 0 && sy[q] * dy >= 0) {
                    int b = 1 + q * 19 + (r - 1);
                    if (n[b] >= 40) { S.ok = false; continue; }
                    px[b][n[b]++] = (short)p;
                }
        }
    int ord[NBIN] = {};
    for (int k = 0; k < NBIN; ++k) ord[k] = k;
    for (int a = 0; a < NBIN; ++a) {
        int best = a;
        for (int c = a + 1; c < NBIN; ++c)
            if (n[ord[c]] > n[ord[best]]) best = c;
        int t = ord[a]; ord[a] = ord[best]; ord[best] = t;
    }
    for (int l = 0; l < 64; ++l) {
        S.binA[l] = (unsigned char)ord[l];
        S.binB[l] = (l >= 51) ? (unsigned char)ord[64 + (l - 51)]
                              : (unsigned char)DUMMY_BIN;
        if (n[ord[l]] > MAX1) S.ok = false;
        if (l >= 51 && n[ord[64 + (l - 51)]] > MAX2) S.ok = false;
    }
    {   // greedy bank-aware placement, primary loop
        bool used[64][40] = {};
        for (int s = 0; s < MAX1; ++s) {
            int bankcnt[32] = {};
            for (int l = 0; l < 64; ++l) {
                int bin = S.binA[l], cnt = n[bin];
                int bestp = 0, bestload = 1 << 30; bool haveUnused = false;
                for (int t = 0; t < cnt; ++t)
                    if (!used[l][t]) {
                        int load = bankcnt[px[bin][t] % 32];
                        if (!haveUnused || load < bestload) { haveUnused = true; bestload = load; bestp = t; }
                    }
                if (!haveUnused)
                    for (int t = 0; t < cnt; ++t) {
                        int load = bankcnt[px[bin][t] % 32];
                        if (load < bestload) { bestload = load; bestp = t; }
                    }
                int p = px[bin][bestp];
                if (haveUnused) used[l][bestp] = true;
                S.off1[s][l] = (unsigned short)(p * 4);
                bankcnt[p % 32]++;
            }
        }
        for (int l = 0; l < 64; ++l)
            for (int t = 0; t < n[S.binA[l]]; ++t)
                if (!used[l][t]) S.ok = false;
    }
    {   // secondary loop
        bool used[64][40] = {};
        for (int s = 0; s < MAX2; ++s) {
            int bankcnt[32] = {};
            for (int l = 0; l < 64; ++l) {
                if (S.binB[l] == DUMMY_BIN) {
                    S.off2[s][l] = (unsigned short)((l % 32) * 4);
                    continue;
                }
                int bin = S.binB[l], cnt = n[bin];
                int bestp = 0, bestload = 1 << 30; bool haveUnused = false;
                for (int t = 0; t < cnt; ++t)
                    if (!used[l][t]) {
                        int load = bankcnt[px[bin][t] % 32];
                        if (!haveUnused || load < bestload) { haveUnused = true; bestload = load; bestp = t; }
                    }
                if (!haveUnused)
                    for (int t = 0; t < cnt; ++t) {
                        int load = bankcnt[px[bin][t] % 32];
                        if (load < bestload) { bestload = load; bestp = t; }
                    }
                int p = px[bin][bestp];
                if (haveUnused) used[l][bestp] = true;
                S.off2[s][l] = (unsigned short)(p * 4);
                bankcnt[p % 32]++;
            }
        }
        for (int l = 0; l < 64; ++l)
            if (S.binB[l] != DUMMY_BIN)
                for (int t = 0; t < n[S.binB[l]]; ++t)
                    if (!used[l][t]) S.ok = false;
    }
    return S;
}

static_assert(build_sched().ok, "schedule overflow / unplaced pixel");
__constant__ Sched d_sched = build_sched();

// sbuf per-wave layout: [0..76] bins, [77] dummy, [78..153] circles(q*19+r-1)
__device__ __forceinline__ int term_addr(int k) {
    if (k == 0) return 0;                    // center mask
    if (k >= NMASK) return DUMMY_BIN;        // 153 overridden w/ gmax; >153 -> 0
    int t = k - 1, q = (t >> 1) & 3, rm1 = t >> 3;
    return (t & 1) ? 78 + q * 19 + rm1       // circle
                   : 1 + q * 19 + rm1;       // ring
}

// ---------------------------------------------------------------------------
// Fused kernel: rows in registers across a manual device-scope grid barrier.
// 1024 blocks x 256 thr, __launch_bounds__(256,4) -> 4 blocks/CU co-resident.
// Barrier polls RELAXED (no per-iteration cache invalidate — round-7 lesson);
// acquire/release via a single __threadfence on each side.
// ---------------------------------------------------------------------------
__global__ __launch_bounds__(256, 4) void cac_fused(const float* __restrict__ x,
                                                    float* __restrict__ partial,
                                                    unsigned* __restrict__ barrier_cnt,
                                                    float* __restrict__ out) {
    __shared__ __align__(16) float smap[4][MAP];
    __shared__ float sbuf[4][160];           // bins + circles per wave
    __shared__ float ssqred[4][NROW];
    __shared__ __align__(16) float sinv[NROW];

    const int wave = threadIdx.x >> 6;
    const int lane = threadIdx.x & 63;
    const int bk = blockIdx.x;
    const int pair0 = bk * 32 + wave * MPW;
    const int b = bk >> 5;                   // 32 blocks per batch index

    // hoisted per-lane constants
    const int linA = lane % 19;                          // segment pos (q0-q2)
    const bool inA = lane < 57, inB = lane < 19;
    const int rbA = 1 + lane;                            // lanes>=57 read q3: harmless
    const int rbB = inB ? 58 + lane : DUMMY_BIN;
    const int a0 = term_addr(lane);
    const int a1 = term_addr(lane + 64);
    const int a2 = term_addr(lane + 128);

    // prefetch map 0
    const float4 NEG4 = make_float4(-INFINITY, -INFINITY, -INFINITY, -INFINITY);
    const float4* xp4 = (const float4*)(x + (size_t)pair0 * MAP);
    float4 t0 = xp4[lane], t1 = xp4[64 + lane], t2 = xp4[128 + lane];
    float4 t3 = NEG4;
    if (lane < 4) t3 = xp4[192 + lane];

    float* smw = smap[wave];
    float* sbw = sbuf[wave];
    float sq0 = 0.0f, sq1 = 0.0f, sq2 = 0.0f;
    float r0a[MPW], r1a[MPW], r2a[MPW];      // rows live in registers

    #pragma unroll
    for (int m = 0; m < MPW; ++m) {
        ((float4*)smw)[lane]       = t0;
        ((float4*)smw)[64 + lane]  = t1;
        ((float4*)smw)[128 + lane] = t2;
        if (lane < 4) ((float4*)smw)[192 + lane] = t3;
        float gmax = fmaxf(fmaxf(fmaxf(t0.x, t0.y), fmaxf(t0.z, t0.w)),
                           fmaxf(fmaxf(t1.x, t1.y), fmaxf(t1.z, t1.w)));
        gmax = fmaxf(gmax, fmaxf(fmaxf(t2.x, t2.y), fmaxf(t2.z, t2.w)));
        gmax = fmaxf(gmax, fmaxf(fmaxf(t3.x, t3.y), fmaxf(t3.z, t3.w)));

        if (m < MPW - 1) {   // software-pipeline next map's global loads
            const float4* np4 = (const float4*)(x + (size_t)(pair0 + m + 1) * MAP);
            t0 = np4[lane]; t1 = np4[64 + lane]; t2 = np4[128 + lane];
            t3 = NEG4;
            if (lane < 4) t3 = np4[192 + lane];
        }
        __builtin_amdgcn_wave_barrier();     // keep LDS writes before reads

        // bank-scheduled gather (init 0 == masked-max clamp)
        const char* base = (const char*)smw;
        float m1 = 0.0f, m2v = 0.0f;
        #pragma unroll
        for (int s = 0; s < MAX1; ++s)
            m1 = fmaxf(m1, *(const float*)(base + d_sched.off1[s][lane]));
        #pragma unroll
        for (int s = 0; s < MAX2; ++s)
            m2v = fmaxf(m2v, *(const float*)(base + d_sched.off2[s][lane]));
        sbw[d_sched.binA[lane]] = m1;
        sbw[d_sched.binB[lane]] = m2v;       // dummy slot absorbs pad lanes

        #pragma unroll
        for (int off = 32; off; off >>= 1)
            gmax = fmaxf(gmax, __shfl_xor(gmax, off, 64));
        __builtin_amdgcn_wave_barrier();

        // segmented shuffle prefix-max over rings -> circles
        float cval = sbw[0];
        float rA = fmaxf(sbw[rbA], cval);    // rings: q=lane/19, r=lane%19+1
        float rB = fmaxf(sbw[rbB], cval);    // q3 rings on lanes 0..18
        #pragma unroll
        for (int s = 1; s <= 16; s <<= 1) {
            float uA = __shfl_up(rA, s, 64);
            float uB = __shfl_up(rB, s, 64);
            if (linA >= s) rA = fmaxf(rA, uA);
            if (lane >= s) rB = fmaxf(rB, uB);
        }
        if (inA) sbw[78 + lane] = rA;
        if (inB) sbw[135 + lane] = rB;
        __builtin_amdgcn_wave_barrier();

        // terms from one LDS read each -> registers
        float r0 = sbw[a0];
        float r1 = sbw[a1];
        float r2 = sbw[a2];
        r2 = (lane == 25) ? gmax : (lane < 26 ? r2 : 0.0f);  // k=153 / pads
        r0a[m] = r0; r1a[m] = r1; r2a[m] = r2;
        sq0 += r0 * r0; sq1 += r1 * r1; sq2 += r2 * r2;
        __builtin_amdgcn_wave_barrier();     // next map's bin writes must not race
    }

    // block-level partial sum of squares -> global (786 KB total)
    ssqred[wave][lane]       = sq0;
    ssqred[wave][lane + 64]  = sq1;
    ssqred[wave][lane + 128] = sq2;
    __syncthreads();
    if (threadIdx.x < NROW) {
        int t = threadIdx.x;
        partial[(size_t)bk * NROW + t] =
            ssqred[0][t] + ssqred[1][t] + ssqred[2][t] + ssqred[3][t];
    }

    // ---- manual grid barrier: RELAXED poll (no inv storm), fenced once ----
    __threadfence();                         // release: partial[] visible device-wide
    __syncthreads();
    if (threadIdx.x == 0) {
        __hip_atomic_fetch_add(barrier_cnt, 1u, __ATOMIC_RELAXED,
                               __HIP_MEMORY_SCOPE_AGENT);
        while (__hip_atomic_load(barrier_cnt, __ATOMIC_RELAXED,
                                 __HIP_MEMORY_SCOPE_AGENT) < (unsigned)NBLK)
            __builtin_amdgcn_s_sleep(32);    // ~2K cycles between polls
    }
    __syncthreads();
    __threadfence();                         // acquire for all threads

    // ---- redundant per-block norm reduce: 32 partial rows of own b (L2) ----
    if (threadIdx.x < NROW) {
        int t = threadIdx.x;
        const float* p = partial + (size_t)(b * 32) * NROW + t;
        float s = 0.0f;
        #pragma unroll
        for (int j = 0; j < 32; ++j) s += p[j * NROW];   // coalesced over t
        sinv[t] = (t < NTERM) ? 1.0f / (sqrtf(s) + 1e-6f) : 0.0f;
    }
    __syncthreads();

    // ---- dot(row, invn) from registers; shuffle-reduce per map ----
    float w0 = sinv[lane];
    float w1 = sinv[64 + lane];
    float w2 = sinv[128 + lane];             // pads are 0
    #pragma unroll
    for (int m = 0; m < MPW; ++m) {
        float d = r0a[m] * w0 + r1a[m] * w1 + r2a[m] * w2;
        #pragma unroll
        for (int off = 32; off; off >>= 1) d += __shfl_xor(d, off, 64);
        if (lane == 0) out[pair0 + m] = d;
    }
}

extern "C" void kernel_launch(void* const* d_in, const int* in_sizes, int n_in,
                              void* d_out, int out_size, void* d_ws, size_t ws_size,
                              hipStream_t stream) {
    const float* x = (const float*)d_in[0];
    float* out = (float*)d_out;

    unsigned* barrier_cnt = (unsigned*)d_ws;                  // [0..255] barrier
    float* partial = (float*)((char*)d_ws + 256);             // 1024*192 f32 = 786 KB

    hipMemsetAsync(d_ws, 0, 256, stream);                     // graph-capture legal
    cac_fused<<<NBLK, 256, 0, stream>>>(x, partial, barrier_cnt, out);
}

// Round 9
// 171.032 us; speedup vs baseline: 2.8371x; 2.4503x over previous
//
#include <hip/hip_runtime.h>
#include <math.h>

// Problem constants
#define B_DIM 32
#define C_DIM 1024
#define MAP 784
#define NMASK 153
#define NTERM 154          // 153 masks + global-max term
#define NROW 192           // padded row length (3 x 64 lanes; pads = 0)
#define NBIN 77            // 0=center, 1 + q*19 + (r-1)
#define DUMMY_BIN 77
#define NW1 28             // array cap, primary windows (loop trip = ns1)
#define NW2 8              // array cap, secondary windows (loop trip = ns2)
#define MPW 8              // maps per wave; 1024 blocks x 4 waves x 8 = 32768

// ---------------------------------------------------------------------------
// Compile-time gather schedule: each lane owns 1-2 bins; bin pixels covered by
// even-aligned 2-float WINDOWS (ds_read_b64) with per-half validity bits.
// Masked-out halves contribute 0.0f == the masked-max clamp floor, so padding
// (idempotent repeat of a real window) and half-masking are both exact.
// enc = w | ex<<14 | ey<<15, window w covers pixels {2w, 2w+1}.
// ---------------------------------------------------------------------------
struct Sched {
    unsigned short w1[NW1][64];
    unsigned short w2[NW2][64];
    unsigned char  binA[64];
    unsigned char  binB[64];   // DUMMY_BIN for lanes without a 2nd bin
    int ns1, ns2;
    bool ok;
};

constexpr Sched build_sched() {
    Sched S{};
    S.ok = true;
    short px[NBIN][40] = {};
    int   n[NBIN] = {};
    for (int i = 0; i < 28; ++i)
        for (int j = 0; j < 28; ++j) {
            int dy = i - 14, dx = j - 14, r2 = dx * dx + dy * dy;
            int p = i * 28 + j;
            if (r2 == 0) { px[0][n[0]++] = (short)p; continue; }
            if (r2 > 361) continue;            // r2>361: in NO mask
            int r = 0; while (r * r < r2) ++r; // ceil(sqrt), 1..19
            const int sx[4] = {1, -1, 1, -1}, sy[4] = {1, 1, -1, -1};
            for (int q = 0; q < 4; ++q)
                if (sx[q] * dx >= 0 && sy[q] * dy >= 0) {
                    int b = 1 + q * 19 + (r - 1);
                    if (n[b] >= 40) { S.ok = false; continue; }
                    px[b][n[b]++] = (short)p;
                }
        }
    // order bins by size descending
    int ord[NBIN] = {};
    for (int k = 0; k < NBIN; ++k) ord[k] = k;
    for (int a = 0; a < NBIN; ++a) {
        int best = a;
        for (int c = a + 1; c < NBIN; ++c)
            if (n[ord[c]] > n[ord[best]]) best = c;
        int t = ord[a]; ord[a] = ord[best]; ord[best] = t;
    }
    for (int l = 0; l < 64; ++l) {
        S.binA[l] = (unsigned char)ord[l];
        S.binB[l] = (l >= 51) ? (unsigned char)ord[64 + (l - 51)]
                              : (unsigned char)DUMMY_BIN;
        if (n[ord[l]] < 1) S.ok = false;
    }

    // ---- primary windows ----
    int wlist[64][NW1] = {};
    int wcnt[64] = {};
    for (int l = 0; l < 64; ++l) {
        bool has[784] = {};
        int bin = S.binA[l];
        for (int t = 0; t < n[bin]; ++t) has[px[bin][t]] = true;
        int c = 0;
        for (int w = 0; w < 392; ++w) {
            bool ex = has[2 * w], ey = has[2 * w + 1];
            if (ex || ey) {
                if (c >= NW1) { S.ok = false; break; }
                wlist[l][c++] = w | (ex ? 0x4000 : 0) | (ey ? 0x8000 : 0);
            }
        }
        wcnt[l] = c;
        if (c < 1) S.ok = false;
    }
    int ns1 = 0;
    for (int l = 0; l < 64; ++l) if (wcnt[l] > ns1) ns1 = wcnt[l];
    S.ns1 = ns1;
    {   // bank-pair-aware greedy slot ordering (b64 uses bank pair w%16)
        bool used[64][NW1] = {};
        for (int s = 0; s < ns1; ++s) {
            int pcnt[16] = {};
            for (int l = 0; l < 64; ++l) {
                int cnt = wcnt[l], bestt = -1, bestload = 1 << 30;
                for (int t = 0; t < cnt; ++t)
                    if (!used[l][t]) {
                        int load = pcnt[(wlist[l][t] & 0x1FF) % 16];
                        if (load < bestload) { bestload = load; bestt = t; }
                    }
                int enc;
                if (bestt >= 0) { used[l][bestt] = true; enc = wlist[l][bestt]; }
                else enc = wlist[l][s % cnt];        // idempotent repeat pad
                S.w1[s][l] = (unsigned short)enc;
                pcnt[(enc & 0x1FF) % 16]++;
            }
        }
        for (int l = 0; l < 64; ++l)
            for (int t = 0; t < wcnt[l]; ++t)
                if (!used[l][t]) S.ok = false;       // full coverage
    }

    // ---- secondary windows (lanes 51..63) ----
    int wlist2[64][NW2] = {};
    int wcnt2[64] = {};
    for (int l = 51; l < 64; ++l) {
        bool has[784] = {};
        int bin = S.binB[l];
        for (int t = 0; t < n[bin]; ++t) has[px[bin][t]] = true;
        int c = 0;
        for (int w = 0; w < 392; ++w) {
            bool ex = has[2 * w], ey = has[2 * w + 1];
            if (ex || ey) {
                if (c >= NW2) { S.ok = false; break; }
                wlist2[l][c++] = w | (ex ? 0x4000 : 0) | (ey ? 0x8000 : 0);
            }
        }
        wcnt2[l] = c;
        if (c < 1) S.ok = false;
    }
    int ns2 = 1;
    for (int l = 51; l < 64; ++l) if (wcnt2[l] > ns2) ns2 = wcnt2[l];
    S.ns2 = ns2;
    {
        bool used[64][NW2] = {};
        for (int s = 0; s < ns2; ++s) {
            int pcnt[16] = {};
            for (int l = 0; l < 64; ++l) {
                if (l < 51) {                        // no 2nd bin: masked read, spread banks
                    S.w2[s][l] = (unsigned short)((l * 13 + s * 5) % 392);
                    continue;
                }
                int cnt = wcnt2[l], bestt = -1, bestload = 1 << 30;
                for (int t = 0; t < cnt; ++t)
                    if (!used[l][t]) {
                        int load = pcnt[(wlist2[l][t] & 0x1FF) % 16];
                        if (load < bestload) { bestload = load; bestt = t; }
                    }
                int enc;
                if (bestt >= 0) { used[l][bestt] = true; enc = wlist2[l][bestt]; }
                else enc = wlist2[l][s % cnt];
                S.w2[s][l] = (unsigned short)enc;
                pcnt[(enc & 0x1FF) % 16]++;
            }
        }
        for (int l = 51; l < 64; ++l)
            for (int t = 0; t < wcnt2[l]; ++t)
                if (!used[l][t]) S.ok = false;
    }
    return S;
}

static constexpr Sched h_sched = build_sched();
static_assert(h_sched.ok, "schedule overflow / empty bin / unplaced window");
constexpr int NS1 = h_sched.ns1;
constexpr int NS2 = h_sched.ns2;
__constant__ Sched d_sched = h_sched;

// sbuf per-wave layout: [0..76] bins, [77] dummy, [78..153] circles(q*19+r-1)
__device__ __forceinline__ int term_addr(int k) {
    if (k == 0) return 0;                    // center mask
    if (k >= NMASK) return DUMMY_BIN;        // 153 overridden w/ gmax; >153 -> 0
    int t = k - 1, q = (t >> 1) & 3, rm1 = t >> 3;
    return (t & 1) ? 78 + q * 19 + rm1       // circle
                   : 1 + q * 19 + rm1;       // ring
}

// ---------------- K1: rows -> vt (coalesced) + atomic normsq ---------------
__global__ __launch_bounds__(256) void cac_k1(const float* __restrict__ x,
                                              float* __restrict__ vt,
                                              float* __restrict__ normsq) {
    __shared__ __align__(16) float smap[4][MAP];
    __shared__ float sbuf[4][160];           // bins + circles per wave
    __shared__ float ssqred[4][NROW];

    const int wave = threadIdx.x >> 6;
    const int lane = threadIdx.x & 63;
    const int pair0 = blockIdx.x * 32 + wave * MPW;

    // hoisted per-lane constants
    const int linA = lane % 19;                          // segment pos (q0-q2)
    const bool inA = lane < 57, inB = lane < 19;
    const int rbA = 1 + lane;                            // lanes>=57 read q3: harmless
    const int rbB = inB ? 58 + lane : DUMMY_BIN;
    const int a0 = term_addr(lane);
    const int a1 = term_addr(lane + 64);
    const int a2 = term_addr(lane + 128);

    // prefetch map 0
    const float4 NEG4 = make_float4(-INFINITY, -INFINITY, -INFINITY, -INFINITY);
    const float4* xp4 = (const float4*)(x + (size_t)pair0 * MAP);
    float4 t0 = xp4[lane], t1 = xp4[64 + lane], t2 = xp4[128 + lane];
    float4 t3 = NEG4;
    if (lane < 4) t3 = xp4[192 + lane];

    float* smw = smap[wave];
    float* sbw = sbuf[wave];
    float sq0 = 0.0f, sq1 = 0.0f, sq2 = 0.0f;

    #pragma unroll
    for (int m = 0; m < MPW; ++m) {
        ((float4*)smw)[lane]       = t0;
        ((float4*)smw)[64 + lane]  = t1;
        ((float4*)smw)[128 + lane] = t2;
        if (lane < 4) ((float4*)smw)[192 + lane] = t3;
        float gmax = fmaxf(fmaxf(fmaxf(t0.x, t0.y), fmaxf(t0.z, t0.w)),
                           fmaxf(fmaxf(t1.x, t1.y), fmaxf(t1.z, t1.w)));
        gmax = fmaxf(gmax, fmaxf(fmaxf(t2.x, t2.y), fmaxf(t2.z, t2.w)));
        gmax = fmaxf(gmax, fmaxf(fmaxf(t3.x, t3.y), fmaxf(t3.z, t3.w)));

        if (m < MPW - 1) {   // software-pipeline next map's global loads
            const float4* np4 = (const float4*)(x + (size_t)(pair0 + m + 1) * MAP);
            t0 = np4[lane]; t1 = np4[64 + lane]; t2 = np4[128 + lane];
            t3 = NEG4;
            if (lane < 4) t3 = np4[192 + lane];
        }
        __builtin_amdgcn_wave_barrier();     // keep LDS writes before reads

        // windowed b64 gather; masked halves contribute 0.0f (= clamp floor)
        const char* base = (const char*)smw;
        float m1 = 0.0f, m2v = 0.0f;
        #pragma unroll
        for (int s = 0; s < NS1; ++s) {
            unsigned e = d_sched.w1[s][lane];
            float2 v = *(const float2*)(base + (e & 0x1FFu) * 8);
            m1 = fmaxf(m1, fmaxf((e & 0x4000u) ? v.x : 0.0f,
                                 (e & 0x8000u) ? v.y : 0.0f));
        }
        #pragma unroll
        for (int s = 0; s < NS2; ++s) {
            unsigned e = d_sched.w2[s][lane];
            float2 v = *(const float2*)(base + (e & 0x1FFu) * 8);
            m2v = fmaxf(m2v, fmaxf((e & 0x4000u) ? v.x : 0.0f,
                                   (e & 0x8000u) ? v.y : 0.0f));
        }
        sbw[d_sched.binA[lane]] = m1;
        sbw[d_sched.binB[lane]] = m2v;       // dummy slot absorbs pad lanes

        #pragma unroll
        for (int off = 32; off; off >>= 1)
            gmax = fmaxf(gmax, __shfl_xor(gmax, off, 64));
        __builtin_amdgcn_wave_barrier();

        // segmented shuffle prefix-max over rings -> circles
        float cval = sbw[0];
        float rA = fmaxf(sbw[rbA], cval);    // rings: q=lane/19, r=lane%19+1
        float rB = fmaxf(sbw[rbB], cval);    // q3 rings on lanes 0..18
        #pragma unroll
        for (int s = 1; s <= 16; s <<= 1) {
            float uA = __shfl_up(rA, s, 64);
            float uB = __shfl_up(rB, s, 64);
            if (linA >= s) rA = fmaxf(rA, uA);
            if (lane >= s) rB = fmaxf(rB, uB);
        }
        if (inA) sbw[78 + lane] = rA;
        if (inB) sbw[135 + lane] = rB;
        __builtin_amdgcn_wave_barrier();

        // terms from one LDS read each
        float r0 = sbw[a0];
        float r1 = sbw[a1];
        float r2 = sbw[a2];
        r2 = (lane == 25) ? gmax : (lane < 26 ? r2 : 0.0f);  // k=153 / pads

        float* rowp = vt + (size_t)(pair0 + m) * NROW;
        rowp[lane]       = r0;
        rowp[64 + lane]  = r1;
        rowp[128 + lane] = r2;
        sq0 += r0 * r0; sq1 += r1 * r1; sq2 += r2 * r2;
        __builtin_amdgcn_wave_barrier();     // next map's bin writes must not race
    }

    // block partial sum of squares -> one fp32 atomicAdd per term (device scope)
    ssqred[wave][lane]       = sq0;
    ssqred[wave][lane + 64]  = sq1;
    ssqred[wave][lane + 128] = sq2;
    __syncthreads();
    if (threadIdx.x < NROW) {
        int t = threadIdx.x;
        float s = ssqred[0][t] + ssqred[1][t] + ssqred[2][t] + ssqred[3][t];
        atomicAdd(&normsq[(blockIdx.x >> 5) * NROW + t], s);
    }
}

// ---------------- K2: inverse norms from normsq + dot ----------------------
// 256 blocks x 256 threads; block handles 128 consecutive pairs (same b).
__global__ __launch_bounds__(256) void cac_k2(const float* __restrict__ vt,
                                              const float* __restrict__ normsq,
                                              float* __restrict__ out) {
    __shared__ __align__(16) float sinv[NROW];
    const int b = blockIdx.x >> 3;           // 8 blocks per b

    if (threadIdx.x < NROW) {
        float s = normsq[b * NROW + threadIdx.x];
        sinv[threadIdx.x] = (threadIdx.x < NTERM) ? 1.0f / (sqrtf(s) + 1e-6f)
                                                  : 0.0f;
    }
    __syncthreads();

    const int local = threadIdx.x >> 1;      // 0..127
    const int half  = threadIdx.x & 1;
    const int pair  = blockIdx.x * 128 + local;
    const float4* row = (const float4*)(vt + (size_t)pair * NROW + half * 96);
    const float4* w4  = (const float4*)sinv + half * 24;
    float acc = 0.0f;
    #pragma unroll
    for (int i = 0; i < 24; ++i) {
        float4 v = row[i], w = w4[i];
        acc += v.x * w.x + v.y * w.y + v.z * w.z + v.w * w.w;
    }
    acc += __shfl_xor(acc, 1, 64);
    if (!half) out[pair] = acc;
}

extern "C" void kernel_launch(void* const* d_in, const int* in_sizes, int n_in,
                              void* d_out, int out_size, void* d_ws, size_t ws_size,
                              hipStream_t stream) {
    const float* x = (const float*)d_in[0];
    float* out = (float*)d_out;

    float* normsq = (float*)d_ws;                        // 32*192 f32 = 24.6 KB
    float* vt     = normsq + (size_t)B_DIM * NROW;       // 32768*192 f32 = 25.2 MB

    hipMemsetAsync(normsq, 0, (size_t)B_DIM * NROW * sizeof(float), stream);
    cac_k1<<<1024, 256, 0, stream>>>(x, vt, normsq);
    cac_k2<<<256, 256, 0, stream>>>(vt, normsq, out);
}